// Round 12
// baseline (175.367 us; speedup 1.0000x reference)
//
#include <hip/hip_runtime.h>
#include <hip/hip_bf16.h>

#define NN 4096
#define IN_F 512
#define HALF 256
#define FF 64
#define ALPHA 0.2f
#define EPSV 1e-5f
#define CAP1 128
#define CAP2 1024
#define WHB (NN / 8)

typedef unsigned long long u64;
typedef unsigned int u32;
typedef unsigned short u16;
typedef unsigned char u8;

__device__ __forceinline__ float lrelu(float x){ return x > 0.f ? x : ALPHA * x; }

__device__ __forceinline__ float wave_fmax(float v){
    #pragma unroll
    for (int off = 32; off; off >>= 1) v = fmaxf(v, __shfl_xor(v, off, 64));
    return v;
}
__device__ __forceinline__ float wave_fsum(float v){
    #pragma unroll
    for (int off = 32; off; off >>= 1) v += __shfl_xor(v, off, 64);
    return v;
}

// Wave-wide compaction of set bits (one u64 word per lane) into a u16 index list.
__device__ __forceinline__ int build_idx16(u64 bits, int lane, int cap, u16* __restrict__ nbr){
    int pc = __popcll(bits);
    int scan = pc;
    #pragma unroll
    for (int off = 1; off < 64; off <<= 1) {
        int v = __shfl_up(scan, off, 64);
        if (lane >= off) scan += v;
    }
    int total = __shfl(scan, 63, 64);
    int pos = scan - pc;
    while (bits) {
        int b = __builtin_ctzll(bits);
        bits &= bits - 1;
        if (pos < cap) nbr[pos] = (u16)((lane << 6) | b);
        ++pos;
    }
    return total;
}

// ---------------- Kernel 1: fused pack + wh + stat-zero ----------------
// blocks [0,NN):        pack row (coalesced float4 + LDS nibble assembly)
// blocks [NN,NN+WHB):   wh GEMV, 8 rows each
// block  NN+WHB:        zero colsum/colsq (256 floats) for attn's atomic tail
__global__ __launch_bounds__(256) void packwh_kernel(const float* __restrict__ adj,
                                                     u16* __restrict__ pack16,
                                                     const float* __restrict__ h,
                                                     const float* __restrict__ W1,
                                                     const float* __restrict__ W2,
                                                     const float* __restrict__ a,
                                                     float* __restrict__ Wh1,
                                                     float* __restrict__ Wh2,
                                                     float* __restrict__ s11,
                                                     float* __restrict__ s12,
                                                     float* __restrict__ s21,
                                                     float* __restrict__ s22,
                                                     float* __restrict__ colsum) {
    __shared__ float hs[8 * IN_F];       // wh branch; pack overlays its 1 KB nibble buf here
    int tid = threadIdx.x;
    if (blockIdx.x < NN) {
        // ---- pack: 4 coalesced float4 loads -> LDS nibbles -> u16 words ----
        u8* nib = (u8*)hs;
        int i = blockIdx.x;
        const float4* row = (const float4*)(adj + (size_t)i * NN);
        float4 v0 = row[tid];
        float4 v1 = row[256 + tid];
        float4 v2 = row[512 + tid];
        float4 v3 = row[768 + tid];
        nib[tid]       = (u8)((v0.x > 0.f) | ((u32)(v0.y > 0.f) << 1) | ((u32)(v0.z > 0.f) << 2) | ((u32)(v0.w > 0.f) << 3));
        nib[256 + tid] = (u8)((v1.x > 0.f) | ((u32)(v1.y > 0.f) << 1) | ((u32)(v1.z > 0.f) << 2) | ((u32)(v1.w > 0.f) << 3));
        nib[512 + tid] = (u8)((v2.x > 0.f) | ((u32)(v2.y > 0.f) << 1) | ((u32)(v2.z > 0.f) << 2) | ((u32)(v2.w > 0.f) << 3));
        nib[768 + tid] = (u8)((v3.x > 0.f) | ((u32)(v3.y > 0.f) << 1) | ((u32)(v3.z > 0.f) << 2) | ((u32)(v3.w > 0.f) << 3));
        __syncthreads();
        u32 x = ((const u32*)nib)[tid];
        u16 wd = (u16)((x & 0xFu) | ((x >> 4) & 0xF0u) | ((x >> 8) & 0xF00u) | ((x >> 12) & 0xF000u));
        pack16[(size_t)i * 256 + tid] = wd;
    } else if (blockIdx.x < NN + WHB) {
        // ---- wh: 8 rows per block; waves 0-1 -> W1, waves 2-3 -> W2 ----
        int r0 = (blockIdx.x - NN) * 8;
        const float4* hsrc = (const float4*)(h + (size_t)r0 * IN_F);
        float4* hdst = (float4*)hs;
        #pragma unroll
        for (int t = 0; t < 4; ++t) hdst[tid + 256 * t] = hsrc[tid + 256 * t];
        __syncthreads();

        int w = tid >> 6, f = tid & 63;
        int br2 = w >> 1;
        int rbase = (w & 1) * 4;
        const float* W = br2 ? W2 : W1;
        const float4* hw4 = (const float4*)(hs + rbase * IN_F + br2 * HALF);
        float acc0 = 0.f, acc1 = 0.f, acc2 = 0.f, acc3 = 0.f;
        #pragma unroll 4
        for (int k4 = 0; k4 < HALF / 4; ++k4) {
            float4 h0 = hw4[k4];
            float4 h1 = hw4[k4 + IN_F / 4];
            float4 h2 = hw4[k4 + 2 * (IN_F / 4)];
            float4 h3 = hw4[k4 + 3 * (IN_F / 4)];
            int k = k4 << 2;
            float w0 = W[(k + 0) * FF + f];
            float w1 = W[(k + 1) * FF + f];
            float w2 = W[(k + 2) * FF + f];
            float w3 = W[(k + 3) * FF + f];
            acc0 += h0.x * w0 + h0.y * w1 + h0.z * w2 + h0.w * w3;
            acc1 += h1.x * w0 + h1.y * w1 + h1.z * w2 + h1.w * w3;
            acc2 += h2.x * w0 + h2.y * w1 + h2.z * w2 + h2.w * w3;
            acc3 += h3.x * w0 + h3.y * w1 + h3.z * w2 + h3.w * w3;
        }
        float* Wh = br2 ? Wh2 : Wh1;
        int rr = r0 + rbase;
        Wh[(size_t)(rr + 0) * FF + f] = acc0;
        Wh[(size_t)(rr + 1) * FF + f] = acc1;
        Wh[(size_t)(rr + 2) * FF + f] = acc2;
        Wh[(size_t)(rr + 3) * FF + f] = acc3;

        float a1 = a[f], a2 = a[64 + f];
        #pragma unroll
        for (int r = 0; r < 4; ++r) {
            float acc = (r == 0) ? acc0 : (r == 1) ? acc1 : (r == 2) ? acc2 : acc3;
            float v1 = acc * a1, v2 = acc * a2;
            #pragma unroll
            for (int off = 32; off; off >>= 1) {
                v1 += __shfl_down(v1, off, 64);
                v2 += __shfl_down(v2, off, 64);
            }
            if (f == 0) {
                if (br2 == 0) { s11[rr + r] = v1; s12[rr + r] = v2; }
                else          { s21[rr + r] = v1; s22[rr + r] = v2; }
            }
        }
    } else {
        // ---- zero the 256 global stat accumulators (colsum[128] ++ colsq[128]) ----
        colsum[tid] = 0.f;
    }
}

// ---------------- Kernel 2: fused attention (1 wave = 1 row, both hops) + stats tail ----------------
__global__ __launch_bounds__(256) void attn_kernel(const u64* __restrict__ packA,
                                                   const float* __restrict__ Wh1,
                                                   const float* __restrict__ Wh2,
                                                   const float* __restrict__ s11,
                                                   const float* __restrict__ s12,
                                                   const float* __restrict__ s21,
                                                   const float* __restrict__ s22,
                                                   float* __restrict__ hp,
                                                   float* __restrict__ colsum,
                                                   float* __restrict__ colsq) {
    __shared__ u16   nbr1s[4][CAP1];
    __shared__ u16   nbr2s[4][CAP2];
    __shared__ float evs[4][CAP2];

    int tid = threadIdx.x;
    int w = tid >> 6, lane = tid & 63;
    int i = blockIdx.x * 4 + w;

    u16*   nbr1 = nbr1s[w];
    u16*   nbr2 = nbr2s[w];
    float* ev   = evs[w];

    // ---- 1-hop list ----
    int t1 = build_idx16(packA[(size_t)i * 64 + lane], lane, CAP1, nbr1);
    int c1 = min(t1, CAP1);

    // ---- hop-1: softmax + gather (lane = column), 8-wide ILP ----
    float out1;
    if (c1 > 0) {
        int c1p = (c1 + 7) & ~7;
        if (lane < c1p - c1) { nbr1[c1 + lane] = 0; }
        float s11i = s11[i];
        float lm = -3.4e38f;
        for (int n = lane; n < c1; n += 64) {
            float e = lrelu(s11i + s12[nbr1[n]]);
            ev[n] = e;
            lm = fmaxf(lm, e);
        }
        float m = wave_fmax(lm);
        float ls = 0.f;
        for (int n = lane; n < c1; n += 64) {
            float p = __expf(ev[n] - m);
            ev[n] = p;
            ls += p;
        }
        float invZ = 1.f / wave_fsum(ls);
        if (lane < c1p - c1) { ev[c1 + lane] = 0.f; }
        float a0 = 0.f, a1 = 0.f, a2 = 0.f, a3 = 0.f;
        for (int n = 0; n < c1p; n += 8) {
            ushort4 nA = *(const ushort4*)&nbr1[n];
            ushort4 nB = *(const ushort4*)&nbr1[n + 4];
            float4  wA = *(const float4*)&ev[n];
            float4  wB = *(const float4*)&ev[n + 4];
            float q0 = Wh1[(int)nA.x * FF + lane];
            float q1 = Wh1[(int)nA.y * FF + lane];
            float q2 = Wh1[(int)nA.z * FF + lane];
            float q3 = Wh1[(int)nA.w * FF + lane];
            float q4 = Wh1[(int)nB.x * FF + lane];
            float q5 = Wh1[(int)nB.y * FF + lane];
            float q6 = Wh1[(int)nB.z * FF + lane];
            float q7 = Wh1[(int)nB.w * FF + lane];
            a0 += wA.x * q0 + wB.x * q4;
            a1 += wA.y * q1 + wB.y * q5;
            a2 += wA.z * q2 + wB.z * q6;
            a3 += wA.w * q3 + wB.w * q7;
        }
        out1 = ((a0 + a1) + (a2 + a3)) * invZ;
    } else {
        float a0 = 0.f, a1 = 0.f, a2 = 0.f, a3 = 0.f;
        for (int n = 0; n < NN; n += 4) {
            a0 += Wh1[(n + 0) * FF + lane];
            a1 += Wh1[(n + 1) * FF + lane];
            a2 += Wh1[(n + 2) * FF + lane];
            a3 += Wh1[(n + 3) * FF + lane];
        }
        out1 = ((a0 + a1) + (a2 + a3)) * (1.f / NN);
    }
    hp[(size_t)i * 128 + lane] = out1;

    // ---- 2-hop mask: OR of neighbor bit-rows, 4 independent accumulators ----
    u64 w0 = 0, w1 = 0, w2 = 0, w3 = 0;
    {
        int n = 0;
        for (; n + 4 <= c1; n += 4) {
            w0 |= packA[(int)nbr1[n + 0] * 64 + lane];
            w1 |= packA[(int)nbr1[n + 1] * 64 + lane];
            w2 |= packA[(int)nbr1[n + 2] * 64 + lane];
            w3 |= packA[(int)nbr1[n + 3] * 64 + lane];
        }
        for (; n < c1; ++n) w0 |= packA[(int)nbr1[n] * 64 + lane];
    }
    u64 word = (w0 | w1) | (w2 | w3);
    if (lane == (i >> 6)) word &= ~(1ull << (i & 63));   // zero adj2 diagonal

    int t2 = build_idx16(word, lane, CAP2, nbr2);
    int c2 = min(t2, CAP2);

    // ---- hop-2: softmax + gather, 8-wide ILP ----
    float out2;
    if (c2 > 0) {
        int c2p = (c2 + 7) & ~7;
        if (lane < c2p - c2) { nbr2[c2 + lane] = 0; }
        float s21i = s21[i];
        float lm = -3.4e38f;
        for (int n = lane; n < c2; n += 64) {
            float e = lrelu(s21i + s22[nbr2[n]]);
            ev[n] = e;
            lm = fmaxf(lm, e);
        }
        float m = wave_fmax(lm);
        float ls = 0.f;
        for (int n = lane; n < c2; n += 64) {
            float p = __expf(ev[n] - m);
            ev[n] = p;
            ls += p;
        }
        float invZ = 1.f / wave_fsum(ls);
        if (lane < c2p - c2) { ev[c2 + lane] = 0.f; }
        float a0 = 0.f, a1 = 0.f, a2 = 0.f, a3 = 0.f;
        for (int n = 0; n < c2p; n += 8) {
            ushort4 nA = *(const ushort4*)&nbr2[n];
            ushort4 nB = *(const ushort4*)&nbr2[n + 4];
            float4  wA = *(const float4*)&ev[n];
            float4  wB = *(const float4*)&ev[n + 4];
            float q0 = Wh2[(int)nA.x * FF + lane];
            float q1 = Wh2[(int)nA.y * FF + lane];
            float q2 = Wh2[(int)nA.z * FF + lane];
            float q3 = Wh2[(int)nA.w * FF + lane];
            float q4 = Wh2[(int)nB.x * FF + lane];
            float q5 = Wh2[(int)nB.y * FF + lane];
            float q6 = Wh2[(int)nB.z * FF + lane];
            float q7 = Wh2[(int)nB.w * FF + lane];
            a0 += wA.x * q0 + wB.x * q4;
            a1 += wA.y * q1 + wB.y * q5;
            a2 += wA.z * q2 + wB.z * q6;
            a3 += wA.w * q3 + wB.w * q7;
        }
        out2 = ((a0 + a1) + (a2 + a3)) * invZ;
    } else {
        float a0 = 0.f, a1 = 0.f, a2 = 0.f, a3 = 0.f;
        for (int n = 0; n < NN; n += 4) {
            a0 += Wh2[(n + 0) * FF + lane];
            a1 += Wh2[(n + 1) * FF + lane];
            a2 += Wh2[(n + 2) * FF + lane];
            a3 += Wh2[(n + 3) * FF + lane];
        }
        out2 = ((a0 + a1) + (a2 + a3)) * (1.f / NN);
    }
    hp[(size_t)i * 128 + 64 + lane] = out2;

    // ---- stats tail: per-block column partials in (now dead) ev slices, then atomics ----
    // Each wave writes only within its own evs[w] (gather already done for this wave).
    ev[lane]       = out1;
    ev[64 + lane]  = out1 * out1;
    ev[128 + lane] = out2;
    ev[192 + lane] = out2 * out2;
    __syncthreads();
    if (tid < 128) {
        int base = (tid < 64) ? 0 : 64;       // 0 -> out1 cols, 64 -> out2 cols
        int c = tid & 63;
        float s = evs[0][base * 2 + c]      + evs[1][base * 2 + c]
                + evs[2][base * 2 + c]      + evs[3][base * 2 + c];
        float q = evs[0][base * 2 + 64 + c] + evs[1][base * 2 + 64 + c]
                + evs[2][base * 2 + 64 + c] + evs[3][base * 2 + 64 + c];
        atomicAdd(&colsum[base + c], s);
        atomicAdd(&colsq[base + c], q);
    }
}

// ---------------- Kernel 3: batchnorm + lrelu (reads colsum/colsq directly) ----------------
__global__ __launch_bounds__(256) void normf_kernel(float* __restrict__ hp,
                                                    const float* __restrict__ colsum,
                                                    const float* __restrict__ colsq,
                                                    const float* __restrict__ gamma,
                                                    const float* __restrict__ beta) {
    __shared__ float cmean[128], cginv[128], cbeta[128];
    int tid = threadIdx.x;
    if (tid < 128) {
        float mean = colsum[tid] * (1.f / NN);
        float var = colsq[tid] * (1.f / NN) - mean * mean;
        cmean[tid] = mean;
        cginv[tid] = rsqrtf(var + EPSV) * gamma[tid];
        cbeta[tid] = beta[tid];
    }
    __syncthreads();

    size_t idx = (size_t)blockIdx.x * 256 + tid;
    if (idx < (size_t)NN * 32) {
        int cb = (int)((idx << 2) & 127);
        float4 v = ((const float4*)hp)[idx];
        float r[4] = {v.x, v.y, v.z, v.w};
        #pragma unroll
        for (int t = 0; t < 4; ++t) {
            int c = cb + t;
            r[t] = lrelu((r[t] - cmean[c]) * cginv[c] + cbeta[c]);
        }
        ((float4*)hp)[idx] = make_float4(r[0], r[1], r[2], r[3]);
    }
}

extern "C" void kernel_launch(void* const* d_in, const int* in_sizes, int n_in,
                              void* d_out, int out_size, void* d_ws, size_t ws_size,
                              hipStream_t stream) {
    const float* h     = (const float*)d_in[0];
    const float* adj   = (const float*)d_in[1];
    const float* W1    = (const float*)d_in[2];
    const float* W2    = (const float*)d_in[3];
    const float* a     = (const float*)d_in[4];
    const float* gamma = (const float*)d_in[5];
    const float* beta  = (const float*)d_in[6];
    float* hp = (float*)d_out;   // [4096, 128]

    u64* packA  = (u64*)d_ws;                         // 2 MB (written as u16, read as u64)
    float* Wh1  = (float*)(packA + (size_t)NN * 64);  // 1 MB
    float* Wh2  = Wh1 + (size_t)NN * FF;              // 1 MB
    float* s11  = Wh2 + (size_t)NN * FF;
    float* s12  = s11 + NN;
    float* s21  = s12 + NN;
    float* s22  = s21 + NN;
    float* colsum = s22 + NN;                         // 128
    float* colsq  = colsum + 128;                     // 128 (contiguous after colsum)

    packwh_kernel<<<NN + WHB + 1, 256, 0, stream>>>(adj, (u16*)packA, h, W1, W2, a,
                                                    Wh1, Wh2, s11, s12, s21, s22, colsum);
    attn_kernel<<<NN / 4, 256, 0, stream>>>(packA, Wh1, Wh2, s11, s12, s21, s22,
                                            hp, colsum, colsq);
    normf_kernel<<<(NN * 32 + 255) / 256, 256, 0, stream>>>(hp, colsum, colsq, gamma, beta);
}

// Round 13
// 164.151 us; speedup vs baseline: 1.0683x; 1.0683x over previous
//
#include <hip/hip_runtime.h>
#include <hip/hip_bf16.h>

#define NN 4096
#define IN_F 512
#define HALF 256
#define FF 64
#define ALPHA 0.2f
#define EPSV 1e-5f
#define CAP1 128
#define CAP2 1024

typedef unsigned long long u64;
typedef unsigned int u32;
typedef unsigned short u16;
typedef unsigned char u8;

__device__ __forceinline__ float lrelu(float x){ return x > 0.f ? x : ALPHA * x; }

__device__ __forceinline__ float wave_fmax(float v){
    #pragma unroll
    for (int off = 32; off; off >>= 1) v = fmaxf(v, __shfl_xor(v, off, 64));
    return v;
}
__device__ __forceinline__ float wave_fsum(float v){
    #pragma unroll
    for (int off = 32; off; off >>= 1) v += __shfl_xor(v, off, 64);
    return v;
}

// Wave-wide compaction of set bits (one u64 word per lane) into a u16 index list.
__device__ __forceinline__ int build_idx16(u64 bits, int lane, int cap, u16* __restrict__ nbr){
    int pc = __popcll(bits);
    int scan = pc;
    #pragma unroll
    for (int off = 1; off < 64; off <<= 1) {
        int v = __shfl_up(scan, off, 64);
        if (lane >= off) scan += v;
    }
    int total = __shfl(scan, 63, 64);
    int pos = scan - pc;
    while (bits) {
        int b = __builtin_ctzll(bits);
        bits &= bits - 1;
        if (pos < cap) nbr[pos] = (u16)((lane << 6) | b);
        ++pos;
    }
    return total;
}

// ---------------- Kernel 1: bit-pack adjacency — coalesced, no cross-lane ops ----------------
__global__ __launch_bounds__(256) void pack_kernel(const float* __restrict__ adj,
                                                   u16* __restrict__ pack16) {
    __shared__ u8 nib[1024];
    int i = blockIdx.x;
    int tid = threadIdx.x;
    const float4* row = (const float4*)(adj + (size_t)i * NN);
    float4 v0 = row[tid];
    float4 v1 = row[256 + tid];
    float4 v2 = row[512 + tid];
    float4 v3 = row[768 + tid];
    nib[tid]       = (u8)((v0.x > 0.f) | ((u32)(v0.y > 0.f) << 1) | ((u32)(v0.z > 0.f) << 2) | ((u32)(v0.w > 0.f) << 3));
    nib[256 + tid] = (u8)((v1.x > 0.f) | ((u32)(v1.y > 0.f) << 1) | ((u32)(v1.z > 0.f) << 2) | ((u32)(v1.w > 0.f) << 3));
    nib[512 + tid] = (u8)((v2.x > 0.f) | ((u32)(v2.y > 0.f) << 1) | ((u32)(v2.z > 0.f) << 2) | ((u32)(v2.w > 0.f) << 3));
    nib[768 + tid] = (u8)((v3.x > 0.f) | ((u32)(v3.y > 0.f) << 1) | ((u32)(v3.z > 0.f) << 2) | ((u32)(v3.w > 0.f) << 3));
    __syncthreads();
    u32 x = ((const u32*)nib)[tid];
    u16 wd = (u16)((x & 0xFu) | ((x >> 4) & 0xF0u) | ((x >> 8) & 0xF00u) | ((x >> 12) & 0xF000u));
    pack16[(size_t)i * 256 + tid] = wd;
}

// ---------------- Kernel 2: Wh GEMV, 8 rows/block, float4 LDS reads ----------------
__global__ __launch_bounds__(256) void wh_kernel(const float* __restrict__ h,
                                                 const float* __restrict__ W1,
                                                 const float* __restrict__ W2,
                                                 const float* __restrict__ a,
                                                 float* __restrict__ Wh1,
                                                 float* __restrict__ Wh2,
                                                 float* __restrict__ s11,
                                                 float* __restrict__ s12,
                                                 float* __restrict__ s21,
                                                 float* __restrict__ s22) {
    __shared__ float hs[8 * IN_F];
    int tid = threadIdx.x;
    int r0 = blockIdx.x * 8;
    const float4* hsrc = (const float4*)(h + (size_t)r0 * IN_F);
    float4* hdst = (float4*)hs;
    #pragma unroll
    for (int t = 0; t < 4; ++t) hdst[tid + 256 * t] = hsrc[tid + 256 * t];
    __syncthreads();

    int w = tid >> 6, f = tid & 63;
    int br2 = w >> 1;
    int rbase = (w & 1) * 4;
    const float* W = br2 ? W2 : W1;
    const float4* hw4 = (const float4*)(hs + rbase * IN_F + br2 * HALF);
    float acc0 = 0.f, acc1 = 0.f, acc2 = 0.f, acc3 = 0.f;
    #pragma unroll 4
    for (int k4 = 0; k4 < HALF / 4; ++k4) {
        float4 h0 = hw4[k4];
        float4 h1 = hw4[k4 + IN_F / 4];
        float4 h2 = hw4[k4 + 2 * (IN_F / 4)];
        float4 h3 = hw4[k4 + 3 * (IN_F / 4)];
        int k = k4 << 2;
        float w0 = W[(k + 0) * FF + f];
        float w1 = W[(k + 1) * FF + f];
        float w2 = W[(k + 2) * FF + f];
        float w3 = W[(k + 3) * FF + f];
        acc0 += h0.x * w0 + h0.y * w1 + h0.z * w2 + h0.w * w3;
        acc1 += h1.x * w0 + h1.y * w1 + h1.z * w2 + h1.w * w3;
        acc2 += h2.x * w0 + h2.y * w1 + h2.z * w2 + h2.w * w3;
        acc3 += h3.x * w0 + h3.y * w1 + h3.z * w2 + h3.w * w3;
    }
    float* Wh = br2 ? Wh2 : Wh1;
    int rr = r0 + rbase;
    Wh[(size_t)(rr + 0) * FF + f] = acc0;
    Wh[(size_t)(rr + 1) * FF + f] = acc1;
    Wh[(size_t)(rr + 2) * FF + f] = acc2;
    Wh[(size_t)(rr + 3) * FF + f] = acc3;

    float a1 = a[f], a2 = a[64 + f];
    #pragma unroll
    for (int r = 0; r < 4; ++r) {
        float acc = (r == 0) ? acc0 : (r == 1) ? acc1 : (r == 2) ? acc2 : acc3;
        float v1 = acc * a1, v2 = acc * a2;
        #pragma unroll
        for (int off = 32; off; off >>= 1) {
            v1 += __shfl_down(v1, off, 64);
            v2 += __shfl_down(v2, off, 64);
        }
        if (f == 0) {
            if (br2 == 0) { s11[rr + r] = v1; s12[rr + r] = v2; }
            else          { s21[rr + r] = v1; s22[rr + r] = v2; }
        }
    }
}

// ---------------- Kernel 3: fused attention, wave-local (1 wave = 1 row, both hops) ----------------
// 16-wide gather unroll (16 L2 loads in flight/wave) + 8-wide 2-hop OR.
__global__ __launch_bounds__(256) void attn_kernel(const u64* __restrict__ packA,
                                                   const float* __restrict__ Wh1,
                                                   const float* __restrict__ Wh2,
                                                   const float* __restrict__ s11,
                                                   const float* __restrict__ s12,
                                                   const float* __restrict__ s21,
                                                   const float* __restrict__ s22,
                                                   float* __restrict__ hp) {
    __shared__ u16   nbr1s[4][CAP1];
    __shared__ u16   nbr2s[4][CAP2];
    __shared__ float evs[4][CAP2];

    int tid = threadIdx.x;
    int w = tid >> 6, lane = tid & 63;
    int i = blockIdx.x * 4 + w;

    u16*   nbr1 = nbr1s[w];
    u16*   nbr2 = nbr2s[w];
    float* ev   = evs[w];

    // ---- 1-hop list ----
    int t1 = build_idx16(packA[(size_t)i * 64 + lane], lane, CAP1, nbr1);
    int c1 = min(t1, CAP1);

    // ---- hop-1: softmax + gather (lane = column), 16-wide ILP ----
    float out1;
    if (c1 > 0) {
        int c1p = (c1 + 15) & ~15;
        if (lane < c1p - c1) { nbr1[c1 + lane] = 0; }
        float s11i = s11[i];
        float lm = -3.4e38f;
        for (int n = lane; n < c1; n += 64) {
            float e = lrelu(s11i + s12[nbr1[n]]);
            ev[n] = e;
            lm = fmaxf(lm, e);
        }
        float m = wave_fmax(lm);
        float ls = 0.f;
        for (int n = lane; n < c1; n += 64) {
            float p = __expf(ev[n] - m);
            ev[n] = p;
            ls += p;
        }
        float invZ = 1.f / wave_fsum(ls);
        if (lane < c1p - c1) { ev[c1 + lane] = 0.f; }
        float a0 = 0.f, a1 = 0.f, a2 = 0.f, a3 = 0.f;
        for (int n = 0; n < c1p; n += 16) {
            ushort4 nA = *(const ushort4*)&nbr1[n];
            ushort4 nB = *(const ushort4*)&nbr1[n + 4];
            ushort4 nC = *(const ushort4*)&nbr1[n + 8];
            ushort4 nD = *(const ushort4*)&nbr1[n + 12];
            float4  wA = *(const float4*)&ev[n];
            float4  wB = *(const float4*)&ev[n + 4];
            float4  wC = *(const float4*)&ev[n + 8];
            float4  wD = *(const float4*)&ev[n + 12];
            float q0  = Wh1[(int)nA.x * FF + lane];
            float q1  = Wh1[(int)nA.y * FF + lane];
            float q2  = Wh1[(int)nA.z * FF + lane];
            float q3  = Wh1[(int)nA.w * FF + lane];
            float q4  = Wh1[(int)nB.x * FF + lane];
            float q5  = Wh1[(int)nB.y * FF + lane];
            float q6  = Wh1[(int)nB.z * FF + lane];
            float q7  = Wh1[(int)nB.w * FF + lane];
            float q8  = Wh1[(int)nC.x * FF + lane];
            float q9  = Wh1[(int)nC.y * FF + lane];
            float q10 = Wh1[(int)nC.z * FF + lane];
            float q11 = Wh1[(int)nC.w * FF + lane];
            float q12 = Wh1[(int)nD.x * FF + lane];
            float q13 = Wh1[(int)nD.y * FF + lane];
            float q14 = Wh1[(int)nD.z * FF + lane];
            float q15 = Wh1[(int)nD.w * FF + lane];
            a0 += wA.x * q0 + wB.x * q4 + wC.x * q8  + wD.x * q12;
            a1 += wA.y * q1 + wB.y * q5 + wC.y * q9  + wD.y * q13;
            a2 += wA.z * q2 + wB.z * q6 + wC.z * q10 + wD.z * q14;
            a3 += wA.w * q3 + wB.w * q7 + wC.w * q11 + wD.w * q15;
        }
        out1 = ((a0 + a1) + (a2 + a3)) * invZ;
    } else {
        float a0 = 0.f, a1 = 0.f, a2 = 0.f, a3 = 0.f;
        for (int n = 0; n < NN; n += 4) {
            a0 += Wh1[(n + 0) * FF + lane];
            a1 += Wh1[(n + 1) * FF + lane];
            a2 += Wh1[(n + 2) * FF + lane];
            a3 += Wh1[(n + 3) * FF + lane];
        }
        out1 = ((a0 + a1) + (a2 + a3)) * (1.f / NN);
    }
    hp[(size_t)i * 128 + lane] = out1;

    // ---- 2-hop mask: OR of neighbor bit-rows, 8 independent accumulators ----
    u64 m0 = 0, m1 = 0, m2 = 0, m3 = 0, m4 = 0, m5 = 0, m6 = 0, m7 = 0;
    {
        int n = 0;
        for (; n + 8 <= c1; n += 8) {
            m0 |= packA[(int)nbr1[n + 0] * 64 + lane];
            m1 |= packA[(int)nbr1[n + 1] * 64 + lane];
            m2 |= packA[(int)nbr1[n + 2] * 64 + lane];
            m3 |= packA[(int)nbr1[n + 3] * 64 + lane];
            m4 |= packA[(int)nbr1[n + 4] * 64 + lane];
            m5 |= packA[(int)nbr1[n + 5] * 64 + lane];
            m6 |= packA[(int)nbr1[n + 6] * 64 + lane];
            m7 |= packA[(int)nbr1[n + 7] * 64 + lane];
        }
        for (; n < c1; ++n) m0 |= packA[(int)nbr1[n] * 64 + lane];
    }
    u64 word = ((m0 | m1) | (m2 | m3)) | ((m4 | m5) | (m6 | m7));
    if (lane == (i >> 6)) word &= ~(1ull << (i & 63));   // zero adj2 diagonal

    int t2 = build_idx16(word, lane, CAP2, nbr2);
    int c2 = min(t2, CAP2);

    // ---- hop-2: softmax + gather, 16-wide ILP ----
    float out2;
    if (c2 > 0) {
        int c2p = (c2 + 15) & ~15;
        if (lane < c2p - c2) { nbr2[c2 + lane] = 0; }
        float s21i = s21[i];
        float lm = -3.4e38f;
        for (int n = lane; n < c2; n += 64) {
            float e = lrelu(s21i + s22[nbr2[n]]);
            ev[n] = e;
            lm = fmaxf(lm, e);
        }
        float m = wave_fmax(lm);
        float ls = 0.f;
        for (int n = lane; n < c2; n += 64) {
            float p = __expf(ev[n] - m);
            ev[n] = p;
            ls += p;
        }
        float invZ = 1.f / wave_fsum(ls);
        if (lane < c2p - c2) { ev[c2 + lane] = 0.f; }
        float a0 = 0.f, a1 = 0.f, a2 = 0.f, a3 = 0.f;
        for (int n = 0; n < c2p; n += 16) {
            ushort4 nA = *(const ushort4*)&nbr2[n];
            ushort4 nB = *(const ushort4*)&nbr2[n + 4];
            ushort4 nC = *(const ushort4*)&nbr2[n + 8];
            ushort4 nD = *(const ushort4*)&nbr2[n + 12];
            float4  wA = *(const float4*)&ev[n];
            float4  wB = *(const float4*)&ev[n + 4];
            float4  wC = *(const float4*)&ev[n + 8];
            float4  wD = *(const float4*)&ev[n + 12];
            float q0  = Wh2[(int)nA.x * FF + lane];
            float q1  = Wh2[(int)nA.y * FF + lane];
            float q2  = Wh2[(int)nA.z * FF + lane];
            float q3  = Wh2[(int)nA.w * FF + lane];
            float q4  = Wh2[(int)nB.x * FF + lane];
            float q5  = Wh2[(int)nB.y * FF + lane];
            float q6  = Wh2[(int)nB.z * FF + lane];
            float q7  = Wh2[(int)nB.w * FF + lane];
            float q8  = Wh2[(int)nC.x * FF + lane];
            float q9  = Wh2[(int)nC.y * FF + lane];
            float q10 = Wh2[(int)nC.z * FF + lane];
            float q11 = Wh2[(int)nC.w * FF + lane];
            float q12 = Wh2[(int)nD.x * FF + lane];
            float q13 = Wh2[(int)nD.y * FF + lane];
            float q14 = Wh2[(int)nD.z * FF + lane];
            float q15 = Wh2[(int)nD.w * FF + lane];
            a0 += wA.x * q0 + wB.x * q4 + wC.x * q8  + wD.x * q12;
            a1 += wA.y * q1 + wB.y * q5 + wC.y * q9  + wD.y * q13;
            a2 += wA.z * q2 + wB.z * q6 + wC.z * q10 + wD.z * q14;
            a3 += wA.w * q3 + wB.w * q7 + wC.w * q11 + wD.w * q15;
        }
        out2 = ((a0 + a1) + (a2 + a3)) * invZ;
    } else {
        float a0 = 0.f, a1 = 0.f, a2 = 0.f, a3 = 0.f;
        for (int n = 0; n < NN; n += 4) {
            a0 += Wh2[(n + 0) * FF + lane];
            a1 += Wh2[(n + 1) * FF + lane];
            a2 += Wh2[(n + 2) * FF + lane];
            a3 += Wh2[(n + 3) * FF + lane];
        }
        out2 = ((a0 + a1) + (a2 + a3)) * (1.f / NN);
    }
    hp[(size_t)i * 128 + 64 + lane] = out2;
}

// ---------------- Kernel 4: per-block column partials (128 blocks) ----------------
__global__ __launch_bounds__(256) void stats_kernel(const float* __restrict__ hp,
                                                    float* __restrict__ ps,
                                                    float* __restrict__ pq) {
    __shared__ float ls[128], lq[128];
    int tid = threadIdx.x;
    if (tid < 128) { ls[tid] = 0.f; lq[tid] = 0.f; }
    __syncthreads();
    float s0 = 0, s1 = 0, s2 = 0, s3 = 0, q0 = 0, q1 = 0, q2 = 0, q3 = 0;
    const float4* hp4 = (const float4*)hp;
    for (size_t idx = (size_t)blockIdx.x * 256 + tid; idx < (size_t)NN * 32;
         idx += (size_t)gridDim.x * 256) {
        float4 v = hp4[idx];
        s0 += v.x; q0 += v.x * v.x;
        s1 += v.y; q1 += v.y * v.y;
        s2 += v.z; q2 += v.z * v.z;
        s3 += v.w; q3 += v.w * v.w;
    }
    int cb = (tid & 31) << 2;
    atomicAdd(&ls[cb + 0], s0); atomicAdd(&lq[cb + 0], q0);
    atomicAdd(&ls[cb + 1], s1); atomicAdd(&lq[cb + 1], q1);
    atomicAdd(&ls[cb + 2], s2); atomicAdd(&lq[cb + 2], q2);
    atomicAdd(&ls[cb + 3], s3); atomicAdd(&lq[cb + 3], q3);
    __syncthreads();
    if (tid < 128) {
        ps[(size_t)blockIdx.x * 128 + tid] = ls[tid];
        pq[(size_t)blockIdx.x * 128 + tid] = lq[tid];
    }
}

// ---------------- Kernel 5: finalize (per-block re-reduce) + batchnorm + lrelu ----------------
__global__ __launch_bounds__(256) void normf_kernel(float* __restrict__ hp,
                                                    const float* __restrict__ ps,
                                                    const float* __restrict__ pq,
                                                    const float* __restrict__ gamma,
                                                    const float* __restrict__ beta) {
    __shared__ float csum[256];
    __shared__ float cmean[128], cginv[128];
    int tid = threadIdx.x;
    {
        const float* src = (tid < 128) ? ps : pq;
        int c = tid & 127;
        float s = 0.f;
        #pragma unroll 8
        for (int b = 0; b < 128; ++b) s += src[b * 128 + c];
        csum[tid] = s;
    }
    __syncthreads();
    if (tid < 128) {
        float mean = csum[tid] * (1.f / NN);
        float var = csum[128 + tid] * (1.f / NN) - mean * mean;
        cmean[tid] = mean;
        cginv[tid] = rsqrtf(var + EPSV) * gamma[tid];
    }
    __syncthreads();

    size_t idx = (size_t)blockIdx.x * 256 + tid;
    if (idx < (size_t)NN * 32) {
        int cb = (int)((idx << 2) & 127);
        float4 v = ((const float4*)hp)[idx];
        float r[4] = {v.x, v.y, v.z, v.w};
        #pragma unroll
        for (int t = 0; t < 4; ++t) {
            int c = cb + t;
            r[t] = lrelu((r[t] - cmean[c]) * cginv[c] + beta[c]);
        }
        ((float4*)hp)[idx] = make_float4(r[0], r[1], r[2], r[3]);
    }
}

extern "C" void kernel_launch(void* const* d_in, const int* in_sizes, int n_in,
                              void* d_out, int out_size, void* d_ws, size_t ws_size,
                              hipStream_t stream) {
    const float* h     = (const float*)d_in[0];
    const float* adj   = (const float*)d_in[1];
    const float* W1    = (const float*)d_in[2];
    const float* W2    = (const float*)d_in[3];
    const float* a     = (const float*)d_in[4];
    const float* gamma = (const float*)d_in[5];
    const float* beta  = (const float*)d_in[6];
    float* hp = (float*)d_out;   // [4096, 128]

    u64* packA  = (u64*)d_ws;                         // 2 MB (written as u16, read as u64)
    float* Wh1  = (float*)(packA + (size_t)NN * 64);  // 1 MB
    float* Wh2  = Wh1 + (size_t)NN * FF;              // 1 MB
    float* s11  = Wh2 + (size_t)NN * FF;
    float* s12  = s11 + NN;
    float* s21  = s12 + NN;
    float* s22  = s21 + NN;
    float* ps   = s22 + NN;                           // 128*128
    float* pq   = ps + 128 * 128;                     // 128*128

    pack_kernel<<<NN, 256, 0, stream>>>(adj, (u16*)packA);
    wh_kernel<<<NN / 8, 256, 0, stream>>>(h, W1, W2, a, Wh1, Wh2, s11, s12, s21, s22);
    attn_kernel<<<NN / 4, 256, 0, stream>>>(packA, Wh1, Wh2, s11, s12, s21, s22, hp);
    stats_kernel<<<128, 256, 0, stream>>>(hp, ps, pq);
    normf_kernel<<<(NN * 32 + 255) / 256, 256, 0, stream>>>(hp, ps, pq, gamma, beta);
}